// Round 4
// baseline (251.342 us; speedup 1.0000x reference)
//
#include <hip/hip_runtime.h>

#define NROWS 4096
#define TLEN  2048
#define BLOCK 512
#define PER_THREAD 4    // TLEN / BLOCK  -> exactly one float4 per thread per array
#define NWAVES (BLOCK/64)
#define LAMBDA 0.95f
#define RBLOCK 256

__global__ __launch_bounds__(BLOCK, 4) void retrace_loss_kernel(
    const float* __restrict__ current_qf,
    const float* __restrict__ target_qf_tp1,
    const float* __restrict__ target_q_tp1,
    const float* __restrict__ rewards,
    const float* __restrict__ pcont,
    const float* __restrict__ logpacs,
    const float* __restrict__ old_logpacs,
    const float* __restrict__ entropy_p,
    const int*   __restrict__ timeout,
    float* __restrict__ partials)            // [NROWS] block partial sums
{
    const int row  = blockIdx.x;
    const int tid  = threadIdx.x;
    const int lane = tid & 63;
    const int wave = tid >> 6;
    // DENSE loads: one float4 per thread per array, lanes contiguous.
    // Each wave instruction covers a 1KB fully-dense span: every 64B line
    // touched exactly once by exactly one instruction (R3 limiter was 2x
    // line traffic from 32B-stride half-density requests).
    const int vidx = (row * TLEN) / 4 + tid;

    float4 vq  = ((const float4*)current_qf   )[vidx];
    float4 vtq = ((const float4*)target_qf_tp1)[vidx];
    float4 vtv = ((const float4*)target_q_tp1 )[vidx];
    float4 vrw = ((const float4*)rewards      )[vidx];
    float4 vpc = ((const float4*)pcont        )[vidx];
    float4 vlp = ((const float4*)logpacs      )[vidx];
    float4 vol = ((const float4*)old_logpacs  )[vidx];
    int4   vto = ((const int4*)  timeout      )[vidx];
    const float ent = entropy_p[0];

    float cq[PER_THREAD]  = {vq.x, vq.y, vq.z, vq.w};
    float tqf[PER_THREAD] = {vtq.x,vtq.y,vtq.z,vtq.w};
    float tv[PER_THREAD]  = {vtv.x,vtv.y,vtv.z,vtv.w};
    float rw[PER_THREAD]  = {vrw.x,vrw.y,vrw.z,vrw.w};
    float pc[PER_THREAD]  = {vpc.x,vpc.y,vpc.z,vpc.w};
    float lp[PER_THREAD]  = {vlp.x,vlp.y,vlp.z,vlp.w};
    float olp[PER_THREAD] = {vol.x,vol.y,vol.z,vol.w};
    int   to[PER_THREAD]  = {vto.x,vto.y,vto.z,vto.w};

    // ---- per-element affine coefficients: q[t] = a[t] + b[t]*q[t+1] ----
    float aco[PER_THREAD], bco[PER_THREAD];
    #pragma unroll
    for (int j = 0; j < PER_THREAD; ++j) {
        float m  = to[j] ? 0.0f : 1.0f;
        float c  = LAMBDA * __expf(fminf(lp[j] - olp[j], 0.0f));
        float mc = m * c;
        bco[j] = pc[j] * mc;
        aco[j] = rw[j] + pc[j] * (tv[j] + ent - mc * tqf[j]);
    }
    // terminal: q[T-1] = target_qf_tp1[:, -1]  (b=0 kills any carry)
    if (tid == BLOCK - 1) { aco[PER_THREAD-1] = tqf[PER_THREAD-1]; bco[PER_THREAD-1] = 0.0f; }

    // ---- per-thread chunk composition (right-to-left): q[lo] = A + B*carry ----
    float A = aco[PER_THREAD-1], Bc = bco[PER_THREAD-1];
    #pragma unroll
    for (int j = PER_THREAD - 2; j >= 0; --j) { A = aco[j] + bco[j] * A; Bc = bco[j] * Bc; }

    // ---- wave-level inclusive suffix scan of affine pairs (Hillis-Steele) ----
    float sA = A, sB = Bc;
    #pragma unroll
    for (int off = 1; off < 64; off <<= 1) {
        float nA = __shfl_down(sA, off);
        float nB = __shfl_down(sB, off);
        if (lane + off < 64) { sA = sA + sB * nA; sB = sB * nB; }
    }
    // exclusive suffix within wave: lane i gets inclusive of lane i+1; lane 63 = identity
    float eA = __shfl_down(sA, 1);
    float eB = __shfl_down(sB, 1);
    if (lane == 63) { eA = 0.0f; eB = 1.0f; }

    // ---- wave carries via LDS (NWAVES waves) ----
    __shared__ float wA[NWAVES], wB[NWAVES], psum[NWAVES];
    if (lane == 0) { wA[wave] = sA; wB[wave] = sB; }  // inclusive at lane 0 = whole-wave comp
    __syncthreads();
    float gA = 0.0f, gB = 1.0f;               // compose waves to the right of this wave
    for (int j = wave + 1; j < NWAVES; ++j) { gA = gA + gB * wA[j]; gB = gB * wB[j]; }

    // carry into this thread's chunk (seed irrelevant: composed B through tail is 0)
    float carry = eA + eB * gA;

    // ---- replay chunk sequentially (matches reference fp32 order), MSE accumulate ----
    float q = carry;
    float sum = 0.0f;
    #pragma unroll
    for (int j = PER_THREAD - 1; j >= 0; --j) {
        q = aco[j] + bco[j] * q;              // q_ret[t]
        float d = cq[j] - q;
        sum += d * d;
    }

    // ---- block reduction -> ONE uncontended store per block (no atomics) ----
    #pragma unroll
    for (int off = 32; off > 0; off >>= 1) sum += __shfl_down(sum, off);
    if (lane == 0) psum[wave] = sum;
    __syncthreads();
    if (tid == 0) {
        float s = 0.0f;
        #pragma unroll
        for (int j = 0; j < NWAVES; ++j) s += psum[j];
        partials[row] = s;
    }
}

// reduce 4096 partials -> mean; single block, no atomics
__global__ __launch_bounds__(RBLOCK) void reduce_kernel(
    const float* __restrict__ partials, float* __restrict__ out)
{
    const int tid  = threadIdx.x;
    const int lane = tid & 63;
    const int wave = tid >> 6;
    float sum = 0.0f;
    #pragma unroll
    for (int k = 0; k < NROWS / RBLOCK / 4; ++k) {          // 4 float4 per thread
        float4 v = ((const float4*)partials)[tid + k * RBLOCK];
        sum += v.x + v.y + v.z + v.w;
    }
    #pragma unroll
    for (int off = 32; off > 0; off >>= 1) sum += __shfl_down(sum, off);
    __shared__ float psum[4];
    if (lane == 0) psum[wave] = sum;
    __syncthreads();
    if (tid == 0) {
        float s = psum[0] + psum[1] + psum[2] + psum[3];
        out[0] = s * (1.0f / ((float)NROWS * (float)TLEN));
    }
}

extern "C" void kernel_launch(void* const* d_in, const int* in_sizes, int n_in,
                              void* d_out, int out_size, void* d_ws, size_t ws_size,
                              hipStream_t stream) {
    const float* current_qf     = (const float*)d_in[0];
    const float* target_qf_tp1  = (const float*)d_in[1];
    const float* target_q_tp1   = (const float*)d_in[2];
    const float* rewards        = (const float*)d_in[3];
    const float* pcont          = (const float*)d_in[4];
    const float* logpacs        = (const float*)d_in[5];
    const float* old_logpacs    = (const float*)d_in[6];
    const float* entropy        = (const float*)d_in[7];
    const int*   timeout        = (const int*)d_in[8];
    float* partials = (float*)d_ws;          // 4096 floats = 16 KB scratch
    float* out = (float*)d_out;

    retrace_loss_kernel<<<NROWS, BLOCK, 0, stream>>>(
        current_qf, target_qf_tp1, target_q_tp1, rewards, pcont,
        logpacs, old_logpacs, entropy, timeout, partials);
    reduce_kernel<<<1, RBLOCK, 0, stream>>>(partials, out);
}

// Round 5
// 224.216 us; speedup vs baseline: 1.1210x; 1.1210x over previous
//
#include <hip/hip_runtime.h>

#define NROWS 4096
#define TLEN  2048
#define BLOCK 512
#define PER_THREAD 4    // TLEN / BLOCK  -> exactly one float4 per thread per array
#define NWAVES (BLOCK/64)
#define LAMBDA 0.95f
#define RBLOCK 256

typedef float v4f __attribute__((ext_vector_type(4)));
typedef int   v4i __attribute__((ext_vector_type(4)));

__global__ __launch_bounds__(BLOCK, 4) void retrace_loss_kernel(
    const float* __restrict__ current_qf,
    const float* __restrict__ target_qf_tp1,
    const float* __restrict__ target_q_tp1,
    const float* __restrict__ rewards,
    const float* __restrict__ pcont,
    const float* __restrict__ logpacs,
    const float* __restrict__ old_logpacs,
    const float* __restrict__ entropy_p,
    const int*   __restrict__ timeout,
    float* __restrict__ partials)            // [NROWS] block partial sums
{
    const int row  = blockIdx.x;
    const int tid  = threadIdx.x;
    const int lane = tid & 63;
    const int wave = tid >> 6;
    // Dense 1KB/wave spans (R4). R5 delta: NONTEMPORAL loads on all streams —
    // inputs are single-use; probe whether the ~3.1 TB/s read wall is a cache
    // allocation-policy artifact (nt bit changes L2/L3 allocate behavior).
    const int vidx = (row * TLEN) / 4 + tid;

    v4f vq  = __builtin_nontemporal_load(((const v4f*)current_qf   ) + vidx);
    v4f vtq = __builtin_nontemporal_load(((const v4f*)target_qf_tp1) + vidx);
    v4f vtv = __builtin_nontemporal_load(((const v4f*)target_q_tp1 ) + vidx);
    v4f vrw = __builtin_nontemporal_load(((const v4f*)rewards      ) + vidx);
    v4f vpc = __builtin_nontemporal_load(((const v4f*)pcont        ) + vidx);
    v4f vlp = __builtin_nontemporal_load(((const v4f*)logpacs      ) + vidx);
    v4f vol = __builtin_nontemporal_load(((const v4f*)old_logpacs  ) + vidx);
    v4i vto = __builtin_nontemporal_load(((const v4i*)timeout      ) + vidx);
    const float ent = entropy_p[0];

    float cq[PER_THREAD]  = {vq.x, vq.y, vq.z, vq.w};
    float tqf[PER_THREAD] = {vtq.x,vtq.y,vtq.z,vtq.w};
    float tv[PER_THREAD]  = {vtv.x,vtv.y,vtv.z,vtv.w};
    float rw[PER_THREAD]  = {vrw.x,vrw.y,vrw.z,vrw.w};
    float pc[PER_THREAD]  = {vpc.x,vpc.y,vpc.z,vpc.w};
    float lp[PER_THREAD]  = {vlp.x,vlp.y,vlp.z,vlp.w};
    float olp[PER_THREAD] = {vol.x,vol.y,vol.z,vol.w};
    int   to[PER_THREAD]  = {vto.x,vto.y,vto.z,vto.w};

    // ---- per-element affine coefficients: q[t] = a[t] + b[t]*q[t+1] ----
    float aco[PER_THREAD], bco[PER_THREAD];
    #pragma unroll
    for (int j = 0; j < PER_THREAD; ++j) {
        float m  = to[j] ? 0.0f : 1.0f;
        float c  = LAMBDA * __expf(fminf(lp[j] - olp[j], 0.0f));
        float mc = m * c;
        bco[j] = pc[j] * mc;
        aco[j] = rw[j] + pc[j] * (tv[j] + ent - mc * tqf[j]);
    }
    // terminal: q[T-1] = target_qf_tp1[:, -1]  (b=0 kills any carry)
    if (tid == BLOCK - 1) { aco[PER_THREAD-1] = tqf[PER_THREAD-1]; bco[PER_THREAD-1] = 0.0f; }

    // ---- per-thread chunk composition (right-to-left): q[lo] = A + B*carry ----
    float A = aco[PER_THREAD-1], Bc = bco[PER_THREAD-1];
    #pragma unroll
    for (int j = PER_THREAD - 2; j >= 0; --j) { A = aco[j] + bco[j] * A; Bc = bco[j] * Bc; }

    // ---- wave-level inclusive suffix scan of affine pairs (Hillis-Steele) ----
    float sA = A, sB = Bc;
    #pragma unroll
    for (int off = 1; off < 64; off <<= 1) {
        float nA = __shfl_down(sA, off);
        float nB = __shfl_down(sB, off);
        if (lane + off < 64) { sA = sA + sB * nA; sB = sB * nB; }
    }
    // exclusive suffix within wave: lane i gets inclusive of lane i+1; lane 63 = identity
    float eA = __shfl_down(sA, 1);
    float eB = __shfl_down(sB, 1);
    if (lane == 63) { eA = 0.0f; eB = 1.0f; }

    // ---- wave carries via LDS (NWAVES waves) ----
    __shared__ float wA[NWAVES], wB[NWAVES], psum[NWAVES];
    if (lane == 0) { wA[wave] = sA; wB[wave] = sB; }  // inclusive at lane 0 = whole-wave comp
    __syncthreads();
    float gA = 0.0f, gB = 1.0f;               // compose waves to the right of this wave
    for (int j = wave + 1; j < NWAVES; ++j) { gA = gA + gB * wA[j]; gB = gB * wB[j]; }

    // carry into this thread's chunk (seed irrelevant: composed B through tail is 0)
    float carry = eA + eB * gA;

    // ---- replay chunk sequentially (matches reference fp32 order), MSE accumulate ----
    float q = carry;
    float sum = 0.0f;
    #pragma unroll
    for (int j = PER_THREAD - 1; j >= 0; --j) {
        q = aco[j] + bco[j] * q;              // q_ret[t]
        float d = cq[j] - q;
        sum += d * d;
    }

    // ---- block reduction -> ONE uncontended store per block (no atomics) ----
    #pragma unroll
    for (int off = 32; off > 0; off >>= 1) sum += __shfl_down(sum, off);
    if (lane == 0) psum[wave] = sum;
    __syncthreads();
    if (tid == 0) {
        float s = 0.0f;
        #pragma unroll
        for (int j = 0; j < NWAVES; ++j) s += psum[j];
        partials[row] = s;
    }
}

// reduce 4096 partials -> mean; single block, no atomics
__global__ __launch_bounds__(RBLOCK) void reduce_kernel(
    const float* __restrict__ partials, float* __restrict__ out)
{
    const int tid  = threadIdx.x;
    const int lane = tid & 63;
    const int wave = tid >> 6;
    float sum = 0.0f;
    #pragma unroll
    for (int k = 0; k < NROWS / RBLOCK / 4; ++k) {          // 4 float4 per thread
        float4 v = ((const float4*)partials)[tid + k * RBLOCK];
        sum += v.x + v.y + v.z + v.w;
    }
    #pragma unroll
    for (int off = 32; off > 0; off >>= 1) sum += __shfl_down(sum, off);
    __shared__ float psum[4];
    if (lane == 0) psum[wave] = sum;
    __syncthreads();
    if (tid == 0) {
        float s = psum[0] + psum[1] + psum[2] + psum[3];
        out[0] = s * (1.0f / ((float)NROWS * (float)TLEN));
    }
}

extern "C" void kernel_launch(void* const* d_in, const int* in_sizes, int n_in,
                              void* d_out, int out_size, void* d_ws, size_t ws_size,
                              hipStream_t stream) {
    const float* current_qf     = (const float*)d_in[0];
    const float* target_qf_tp1  = (const float*)d_in[1];
    const float* target_q_tp1   = (const float*)d_in[2];
    const float* rewards        = (const float*)d_in[3];
    const float* pcont          = (const float*)d_in[4];
    const float* logpacs        = (const float*)d_in[5];
    const float* old_logpacs    = (const float*)d_in[6];
    const float* entropy        = (const float*)d_in[7];
    const int*   timeout        = (const int*)d_in[8];
    float* partials = (float*)d_ws;          // 4096 floats = 16 KB scratch
    float* out = (float*)d_out;

    retrace_loss_kernel<<<NROWS, BLOCK, 0, stream>>>(
        current_qf, target_qf_tp1, target_q_tp1, rewards, pcont,
        logpacs, old_logpacs, entropy, timeout, partials);
    reduce_kernel<<<1, RBLOCK, 0, stream>>>(partials, out);
}